// Round 6
// baseline (212.587 us; speedup 1.0000x reference)
//
#include <hip/hip_runtime.h>
#include <hip/hip_bf16.h>

// N=262144 sentences (uniform 16/bag, contiguous), D=768, C=53
// Y = X * W^T [N x 53] via bf16 MFMA, A-fragments loaded DIRECTLY from global x
// (no staging LDS, no barriers); att_s = Y[s][q_s];
// logits[bag] = sum_s softmax(att)_s * Y[s][:] + bias.
#define DIM    768
#define NC     53
#define NCP    64        // classes padded to 4 MFMA n-tiles
#define MTB    256       // sentences per block (8 waves x 32 rows)
#define NTH    512
#define NSTEPS 24        // 768 / 32

typedef __attribute__((ext_vector_type(8))) short short8;
typedef __attribute__((ext_vector_type(4))) float f32x4;

static __device__ inline unsigned short f2bf(float f) {
    unsigned u = __float_as_uint(f);
    u += 0x7fff + ((u >> 16) & 1);           // RNE
    return (unsigned short)(u >> 16);
}

// ---- kernel 1: W fp32 [53][768] -> bf16 [64][768] in d_ws ----
__global__ void wconv_kernel(const float* __restrict__ W, unsigned short* __restrict__ Wt) {
    const int idx = blockIdx.x * 256 + threadIdx.x;
    if (idx >= NCP * DIM) return;
    const int c = idx / DIM, k = idx - c * DIM;
    Wt[idx] = f2bf((c < NC) ? W[c * DIM + k] : 0.f);
}

// 8 fp32 -> bf16x8 via packed cvt (compiler emits v_cvt_pk_bf16_f32)
static __device__ inline short8 cvt8(const float4 a, const float4 b) {
    union { __hip_bfloat162 h[4]; short8 s; } u;
    u.h[0] = __float22bfloat162_rn(make_float2(a.x, a.y));
    u.h[1] = __float22bfloat162_rn(make_float2(a.z, a.w));
    u.h[2] = __float22bfloat162_rn(make_float2(b.x, b.y));
    u.h[3] = __float22bfloat162_rn(make_float2(b.z, b.w));
    return u.s;
}

__global__ __launch_bounds__(NTH, 4) void bag_attn_mfma2(
    const float* __restrict__ x,              // [N][768] fp32
    const unsigned short* __restrict__ Wt,    // [64][768] bf16
    const float* __restrict__ bias,           // [53]
    const int*   __restrict__ query,          // [N]
    float*       __restrict__ out)            // [B][53]
{
    __shared__ float att_sm[16][16];          // wave-local use only

    const int t   = threadIdx.x;
    const int w   = t >> 6;                   // wave 0..7 -> rows 32w..32w+31
    const int l   = t & 63;
    const int blk = blockIdx.x;
    const int row_g = blk * MTB;

    const int r16 = l & 15;                   // row/col within 16-tile
    const int kq  = l >> 4;                   // k-quarter 0..3

    // A-fragment pointers: lane reads 8 consecutive fp32 of ONE row per step
    const float4* a0p = reinterpret_cast<const float4*>(x)
                      + (size_t)(row_g + 32 * w + r16) * (DIM / 4) + kq * 2;
    const float4* a1p = a0p + 16 * (DIM / 4);
    // B-fragment base offset (row 16*ni + r16, k-offset kq*8)
    const unsigned short* wb = Wt + r16 * DIM + kq * 8;

    f32x4 acc[2][4];
    #pragma unroll
    for (int mi = 0; mi < 2; ++mi)
        #pragma unroll
        for (int ni = 0; ni < 4; ++ni)
            acc[mi][ni] = (f32x4){0.f, 0.f, 0.f, 0.f};

    // ---- software pipeline: A prefetched 2 K-steps ahead ----
    float4 P0a = a0p[0], P0b = a0p[1], P1a = a1p[0], P1b = a1p[1];
    float4 Q0a = a0p[8], Q0b = a0p[9], Q1a = a1p[8], Q1b = a1p[9];

    #pragma unroll
    for (int kk = 0; kk < NSTEPS; kk += 2) {
        // step kk (P buffers)
        {
            const short8 af0 = cvt8(P0a, P0b);
            const short8 af1 = cvt8(P1a, P1b);
            if (kk + 2 < NSTEPS) {
                P0a = a0p[(kk + 2) * 8 + 0]; P0b = a0p[(kk + 2) * 8 + 1];
                P1a = a1p[(kk + 2) * 8 + 0]; P1b = a1p[(kk + 2) * 8 + 1];
            }
            #pragma unroll
            for (int ni = 0; ni < 4; ++ni) {
                const short8 bf = *reinterpret_cast<const short8*>(
                    wb + ni * 16 * DIM + kk * 32);
                acc[0][ni] = __builtin_amdgcn_mfma_f32_16x16x32_bf16(af0, bf, acc[0][ni], 0, 0, 0);
                acc[1][ni] = __builtin_amdgcn_mfma_f32_16x16x32_bf16(af1, bf, acc[1][ni], 0, 0, 0);
            }
        }
        // step kk+1 (Q buffers)
        {
            const short8 ag0 = cvt8(Q0a, Q0b);
            const short8 ag1 = cvt8(Q1a, Q1b);
            if (kk + 3 < NSTEPS) {
                Q0a = a0p[(kk + 3) * 8 + 0]; Q0b = a0p[(kk + 3) * 8 + 1];
                Q1a = a1p[(kk + 3) * 8 + 0]; Q1b = a1p[(kk + 3) * 8 + 1];
            }
            #pragma unroll
            for (int ni = 0; ni < 4; ++ni) {
                const short8 bf = *reinterpret_cast<const short8*>(
                    wb + ni * 16 * DIM + (kk + 1) * 32);
                acc[0][ni] = __builtin_amdgcn_mfma_f32_16x16x32_bf16(ag0, bf, acc[0][ni], 0, 0, 0);
                acc[1][ni] = __builtin_amdgcn_mfma_f32_16x16x32_bf16(ag1, bf, acc[1][ni], 0, 0, 0);
            }
        }
    }

    // ---- epilogue: att extraction (D-layout: col=lane&15, row=kq*4+reg) ----
    #pragma unroll
    for (int mi = 0; mi < 2; ++mi) {
        #pragma unroll
        for (int r = 0; r < 4; ++r) {
            const int s_loc = (kq << 2) + r;
            const int q = query[row_g + 32 * w + 16 * mi + s_loc];
            if ((q & 15) == r16) {            // one lane per row matches
                float v = acc[mi][0][r];
                if ((q >> 4) == 1) v = acc[mi][1][r];
                if ((q >> 4) == 2) v = acc[mi][2][r];
                if ((q >> 4) == 3) v = acc[mi][3][r];
                att_sm[2 * w + mi][s_loc] = v;
            }
        }
    }
    // att_sm rows 2w,2w+1 are written and read by wave w only -> no barrier

    #pragma unroll
    for (int mi = 0; mi < 2; ++mi) {
        const int bag = 2 * w + mi;
        const float4* a4 = reinterpret_cast<const float4*>(&att_sm[bag][0]);
        const float4 A0 = a4[0], A1 = a4[1], A2 = a4[2], A3 = a4[3];
        float mx = fmaxf(fmaxf(fmaxf(A0.x, A0.y), fmaxf(A0.z, A0.w)),
                  fmaxf(fmaxf(fmaxf(A1.x, A1.y), fmaxf(A1.z, A1.w)),
                  fmaxf(fmaxf(fmaxf(A2.x, A2.y), fmaxf(A2.z, A2.w)),
                        fmaxf(fmaxf(A3.x, A3.y), fmaxf(A3.z, A3.w)))));
        float zz = __expf(A0.x-mx)+__expf(A0.y-mx)+__expf(A0.z-mx)+__expf(A0.w-mx)
                 + __expf(A1.x-mx)+__expf(A1.y-mx)+__expf(A1.z-mx)+__expf(A1.w-mx)
                 + __expf(A2.x-mx)+__expf(A2.y-mx)+__expf(A2.z-mx)+__expf(A2.w-mx)
                 + __expf(A3.x-mx)+__expf(A3.y-mx)+__expf(A3.z-mx)+__expf(A3.w-mx);
        const float inv = 1.f / zz;
        float4 As = A0;
        if (kq == 1) As = A1;
        if (kq == 2) As = A2;
        if (kq == 3) As = A3;
        const float w0 = __expf(As.x - mx) * inv;
        const float w1 = __expf(As.y - mx) * inv;
        const float w2 = __expf(As.z - mx) * inv;
        const float w3 = __expf(As.w - mx) * inv;
        #pragma unroll
        for (int ni = 0; ni < 4; ++ni) {
            float p = w0 * acc[mi][ni][0] + w1 * acc[mi][ni][1]
                    + w2 * acc[mi][ni][2] + w3 * acc[mi][ni][3];
            p += __shfl_xor(p, 16, 64);       // sum the 4 k-quarter groups
            p += __shfl_xor(p, 32, 64);
            if (l < 16) {
                const int c = 16 * ni + l;
                if (c < NC)
                    out[(size_t)(blk * 16 + bag) * NC + c] = p + bias[c];
            }
        }
    }
}

extern "C" void kernel_launch(void* const* d_in, const int* in_sizes, int n_in,
                              void* d_out, int out_size, void* d_ws, size_t ws_size,
                              hipStream_t stream) {
    const float* x     = (const float*)d_in[0];   // [N][768]
    const float* W     = (const float*)d_in[1];   // [53][768]
    const float* bias  = (const float*)d_in[2];   // [53]
    const int*   query = (const int*)d_in[4];     // [N]
    float* out = (float*)d_out;                   // [B][53]

    unsigned short* Wt = (unsigned short*)d_ws;   // 64*768*2 = 96 KiB

    const int nrows = in_sizes[0] / DIM;          // 262144
    const int nblk  = nrows / MTB;                // 1024

    wconv_kernel<<<(NCP * DIM + 255) / 256, 256, 0, stream>>>(W, Wt);
    bag_attn_mfma2<<<nblk, NTH, 0, stream>>>(x, Wt, bias, query, out);
}